// Round 2
// baseline (328.828 us; speedup 1.0000x reference)
//
#include <hip/hip_runtime.h>
#include <cstdint>

#define L_SEQ 1024
#define DSRC 512
#define XPL 2097152L   // x / q / k plane stride (elems) = 2048*1024
#define WPL 1048576L   // weight plane stride = 1024*1024

typedef __attribute__((ext_vector_type(8))) short short8;
typedef __attribute__((ext_vector_type(4))) float floatx4;

__device__ __forceinline__ unsigned short f2bf(float f) {
  unsigned int x = __float_as_uint(f);
  x += 0x7fff + ((x >> 16) & 1);   // RNE
  return (unsigned short)(x >> 16);
}
__device__ __forceinline__ float bf2f(unsigned short h) {
  return __uint_as_float((unsigned)h << 16);
}
// 3-way bf16 split: f = h0 + h1 + h2 + O(2^-27 |f|)
__device__ __forceinline__ void split3(float f, unsigned short* h) {
  h[0] = f2bf(f);
  float d = f - bf2f(h[0]);
  h[1] = f2bf(d);
  h[2] = f2bf(d - bf2f(h[1]));
}

// async global->LDS, 16B per lane; dest must be the wave-uniform base
__device__ __forceinline__ void gload_lds16(const void* g, void* l) {
  __builtin_amdgcn_global_load_lds(
      (const __attribute__((address_space(1))) unsigned int*)g,
      (__attribute__((address_space(3))) unsigned int*)l, 16, 0, 0);
}

// ---------------- split the 4 fp32 inputs into 3 bf16 planes each ----------------
__global__ __launch_bounds__(256) void split_inputs_k(
    const float* __restrict__ query, const float* __restrict__ key_t,
    const float* __restrict__ wq, const float* __restrict__ wk,
    ushort* __restrict__ xs, ushort* __restrict__ wsp) {
  int blk = blockIdx.x;
  const float* in; ushort* out; long pl; int idx;
  if (blk < 2048)      { in = query; out = xs;           pl = XPL; idx = blk; }
  else if (blk < 4096) { in = key_t; out = xs + 3 * XPL; pl = XPL; idx = blk - 2048; }
  else if (blk < 5120) { in = wq;    out = wsp;          pl = WPL; idx = blk - 4096; }
  else                 { in = wk;    out = wsp + 3 * WPL; pl = WPL; idx = blk - 5120; }
  long e = (long)idx * 1024 + threadIdx.x * 4;
  float4 v = *(const float4*)(in + e);
  unsigned short h0[3], h1[3], h2[3], h3[3];
  split3(v.x, h0); split3(v.y, h1); split3(v.z, h2); split3(v.w, h3);
#pragma unroll
  for (int s = 0; s < 3; s++) {
    ushort4 u; u.x = h0[s]; u.y = h1[s]; u.z = h2[s]; u.w = h3[s];
    *(ushort4*)(out + s * pl + e) = u;
  }
}

// ---------------- projection GEMM: bf16x6 emulated fp32, global_load_lds + dbuf ----------------
// 512 threads = 8 waves (2x4 over 128x128 tile), BK=32, double-buffered LDS (96KB).
// Epilogue adds bias and writes the bf16x3 split of q/k directly (score reads planes).
// LDS swizzle: 16B col-block q stored at q ^ ((row>>1)&3); source pre-swizzled since
// global_load_lds writes linearly (guide rule 21); read applies the same XOR.
__global__ __launch_bounds__(512, 2) void proj_gemm_k(
    const ushort* __restrict__ xs, const ushort* __restrict__ wsp,
    ushort* __restrict__ qs, ushort* __restrict__ ks,
    const float* __restrict__ bq, const float* __restrict__ bk) {
  __shared__ ushort As[2][3][4096];   // [buf][plane][row*32+col]
  __shared__ ushort Bs[2][3][4096];
  int z = blockIdx.z;
  const ushort* Ab = xs + (long)z * 3 * XPL + (long)blockIdx.y * 128 * 1024;
  const ushort* Bb = wsp + (long)z * 3 * WPL + (long)blockIdx.x * 128 * 1024;

  int tid = threadIdx.x;
  int lane = tid & 63, wv = tid >> 6;     // 8 waves
  int wm = wv >> 2, wn = wv & 3;          // wave tile: 64 rows x 32 cols
  int quad = lane >> 4, l16 = lane & 15;

  // staging: thread t loads the 16B vector that lands at LDS offset t*16 (linear).
  // LDS slot (r, qb) must hold source col-block qb ^ ((r>>1)&3).
  int sr = tid >> 2;                                   // row 0..127
  int scq = (((tid & 3) ^ ((sr >> 1) & 3)) << 3);      // swizzled col (ushorts)

  floatx4 acc[4][2] = {};

  // prologue: stage k0=0 into buf 0
#pragma unroll
  for (int s = 0; s < 3; s++) {
    gload_lds16(Ab + (long)s * XPL + (long)sr * 1024 + scq, &As[0][s][wv * 512]);
    gload_lds16(Bb + (long)s * WPL + (long)sr * 1024 + scq, &Bs[0][s][wv * 512]);
  }
  __syncthreads();

  int cur = 0;
#pragma unroll 2
  for (int t = 0; t < 32; t++) {
    if (t < 31) {   // issue next-tile loads; they overlap this tile's ds_read+MFMA
      int k0 = (t + 1) * 32;
#pragma unroll
      for (int s = 0; s < 3; s++) {
        gload_lds16(Ab + (long)s * XPL + (long)sr * 1024 + k0 + scq, &As[cur ^ 1][s][wv * 512]);
        gload_lds16(Bb + (long)s * WPL + (long)sr * 1024 + k0 + scq, &Bs[cur ^ 1][s][wv * 512]);
      }
    }
    short8 af[3][4];
#pragma unroll
    for (int s = 0; s < 3; s++)
#pragma unroll
      for (int i = 0; i < 4; i++) {
        int row = wm * 64 + i * 16 + l16;
        int qa = (quad ^ ((row >> 1) & 3)) << 3;
        af[s][i] = *(const short8*)(&As[cur][s][row * 32 + qa]);
      }
#pragma unroll
    for (int j = 0; j < 2; j++) {
      int rowb = wn * 32 + j * 16 + l16;
      int boff = rowb * 32 + ((quad ^ ((rowb >> 1) & 3)) << 3);
      short8 b0 = *(const short8*)(&Bs[cur][0][boff]);
      short8 b1 = *(const short8*)(&Bs[cur][1][boff]);
      short8 b2 = *(const short8*)(&Bs[cur][2][boff]);
#pragma unroll
      for (int i = 0; i < 4; i++) {
        // small -> large accumulation (bit-identical order to prior kernel)
        acc[i][j] = __builtin_amdgcn_mfma_f32_16x16x32_bf16(af[1][i], b1, acc[i][j], 0, 0, 0);
        acc[i][j] = __builtin_amdgcn_mfma_f32_16x16x32_bf16(af[0][i], b2, acc[i][j], 0, 0, 0);
        acc[i][j] = __builtin_amdgcn_mfma_f32_16x16x32_bf16(af[2][i], b0, acc[i][j], 0, 0, 0);
        acc[i][j] = __builtin_amdgcn_mfma_f32_16x16x32_bf16(af[0][i], b1, acc[i][j], 0, 0, 0);
        acc[i][j] = __builtin_amdgcn_mfma_f32_16x16x32_bf16(af[1][i], b0, acc[i][j], 0, 0, 0);
        acc[i][j] = __builtin_amdgcn_mfma_f32_16x16x32_bf16(af[0][i], b0, acc[i][j], 0, 0, 0);
      }
    }
    __syncthreads();   // drains prefetch (vmcnt) + guards buf reuse
    cur ^= 1;
  }

  // epilogue: bias + bf16x3 split, write 3 planes (score consumes these directly)
  ushort* Ob = z ? ks : qs;
  const float* bias = z ? bk : bq;
#pragma unroll
  for (int j = 0; j < 2; j++) {
    int col = blockIdx.x * 128 + wn * 32 + j * 16 + l16;
    float bv = bias[col];
#pragma unroll
    for (int i = 0; i < 4; i++) {
#pragma unroll
      for (int r = 0; r < 4; r++) {
        long row = blockIdx.y * 128 + wm * 64 + i * 16 + quad * 4 + r;
        float val = acc[i][j][r] + bv;
        unsigned short h[3]; split3(val, h);
        long e = row * 1024 + col;
#pragma unroll
        for (int s = 0; s < 3; s++) Ob[s * XPL + e] = h[s];
      }
    }
  }
}

// ---------------- score GEMM: S[v] = q_v * k_v^T from pre-split planes ----------------
// Per batch (arg b). 512 threads = 8 waves, 128x128 tile, K=128, BK=32, single-buffer
// LDS 48KB -> 2 blocks/CU for cross-block overlap. No on-the-fly split3 anymore.
__global__ __launch_bounds__(512, 4) void score_gemm_k(
    const ushort* __restrict__ qs, const ushort* __restrict__ ks,
    float* __restrict__ S, int b) {
  __shared__ ushort As[3][4096];
  __shared__ ushort Bs[3][4096];
  int v = blockIdx.z;
  const ushort* Ab = qs + (long)b * 1048576 + v * 128 + (long)blockIdx.y * 131072;
  const ushort* Bb = ks + (long)b * 1048576 + v * 128 + (long)blockIdx.x * 131072;

  int tid = threadIdx.x;
  int lane = tid & 63, wv = tid >> 6;
  int wm = wv >> 2, wn = wv & 3;
  int quad = lane >> 4, l16 = lane & 15;

  int sr = tid >> 2;
  int scq = (((tid & 3) ^ ((sr >> 1) & 3)) << 3);

  floatx4 acc[4][2] = {};

  for (int t = 0; t < 4; t++) {
    int k0 = t * 32;
#pragma unroll
    for (int s = 0; s < 3; s++) {
      gload_lds16(Ab + (long)s * XPL + (long)sr * 1024 + k0 + scq, &As[s][wv * 512]);
      gload_lds16(Bb + (long)s * XPL + (long)sr * 1024 + k0 + scq, &Bs[s][wv * 512]);
    }
    __syncthreads();

    short8 af[3][4];
#pragma unroll
    for (int s = 0; s < 3; s++)
#pragma unroll
      for (int i = 0; i < 4; i++) {
        int row = wm * 64 + i * 16 + l16;
        int qa = (quad ^ ((row >> 1) & 3)) << 3;
        af[s][i] = *(const short8*)(&As[s][row * 32 + qa]);
      }
#pragma unroll
    for (int j = 0; j < 2; j++) {
      int rowb = wn * 32 + j * 16 + l16;
      int boff = rowb * 32 + ((quad ^ ((rowb >> 1) & 3)) << 3);
      short8 b0 = *(const short8*)(&Bs[0][boff]);
      short8 b1 = *(const short8*)(&Bs[1][boff]);
      short8 b2 = *(const short8*)(&Bs[2][boff]);
#pragma unroll
      for (int i = 0; i < 4; i++) {
        acc[i][j] = __builtin_amdgcn_mfma_f32_16x16x32_bf16(af[1][i], b1, acc[i][j], 0, 0, 0);
        acc[i][j] = __builtin_amdgcn_mfma_f32_16x16x32_bf16(af[0][i], b2, acc[i][j], 0, 0, 0);
        acc[i][j] = __builtin_amdgcn_mfma_f32_16x16x32_bf16(af[2][i], b0, acc[i][j], 0, 0, 0);
        acc[i][j] = __builtin_amdgcn_mfma_f32_16x16x32_bf16(af[0][i], b1, acc[i][j], 0, 0, 0);
        acc[i][j] = __builtin_amdgcn_mfma_f32_16x16x32_bf16(af[1][i], b0, acc[i][j], 0, 0, 0);
        acc[i][j] = __builtin_amdgcn_mfma_f32_16x16x32_bf16(af[0][i], b0, acc[i][j], 0, 0, 0);
      }
    }
    __syncthreads();
  }

  float* Sb = S + (long)v * 1048576;
#pragma unroll
  for (int j = 0; j < 2; j++) {
    int col = blockIdx.x * 128 + wn * 32 + j * 16 + l16;
#pragma unroll
    for (int i = 0; i < 4; i++) {
#pragma unroll
      for (int r = 0; r < 4; r++) {
        int row = blockIdx.y * 128 + wm * 64 + i * 16 + quad * 4 + r;
        Sb[(long)row * 1024 + col] = acc[i][j][r];
      }
    }
  }
}

// ---------------- top-8 + softmax, one wave per q-row (per batch) ----------------
__global__ __launch_bounds__(256) void topk_softmax_k(const float* __restrict__ scores,
                                                      float* __restrict__ wts,
                                                      int* __restrict__ idxs) {
  int row = blockIdx.x * 4 + (threadIdx.x >> 6);   // 0..8191 within batch
  int lane = threadIdx.x & 63;
  const float4* s4 = (const float4*)(scores + (long)row * 1024);
  float v[16];
#pragma unroll
  for (int i = 0; i < 4; i++) {
    float4 t4 = s4[i * 64 + lane];
    v[i * 4 + 0] = t4.x; v[i * 4 + 1] = t4.y; v[i * 4 + 2] = t4.z; v[i * 4 + 3] = t4.w;
  }
  // slot i holds column ci = (i>>2)*256 + lane*4 + (i&3)  (ascending in i per lane)
  float topv[8]; int topi[8];
  for (int t = 0; t < 8; t++) {
    float bv = -1e30f; int bi = 1 << 30; int bslot = -1;
#pragma unroll
    for (int i = 0; i < 16; i++) {
      int ci = ((i >> 2) << 8) + (lane << 2) + (i & 3);
      if (v[i] > bv) { bv = v[i]; bi = ci; bslot = i; }
    }
    float rv = bv; int ri = bi;
    for (int off = 32; off; off >>= 1) {
      float ov = __shfl_down(rv, off);
      int oi = __shfl_down(ri, off);
      if (ov > rv || (ov == rv && oi < ri)) { rv = ov; ri = oi; }
    }
    rv = __shfl(rv, 0); ri = __shfl(ri, 0);
    topv[t] = rv; topi[t] = ri;
    if (bslot >= 0 && bi == ri) v[bslot] = -1e30f;
  }
  float m = topv[0], sum = 0.f, e[8];
#pragma unroll
  for (int t = 0; t < 8; t++) { e[t] = __expf(topv[t] - m); sum += e[t]; }
  float inv = 1.0f / sum;
  if (lane < 8) {
    wts[(long)row * 8 + lane] = e[lane] * inv;
    idxs[(long)row * 8 + lane] = topi[lane];
  }
}

// ---------------- gather + weighted sum ----------------
__global__ __launch_bounds__(256) void gather_out_k(const float* __restrict__ src,
                                                    const float* __restrict__ wts,
                                                    const int* __restrict__ idxs,
                                                    float* __restrict__ out) {
  int rowid = blockIdx.x;
  int b = rowid >> 13;
  int tid = threadIdx.x;
  int d4 = tid & 127;
  int w0 = (tid >> 7) << 1;
  const float4* s4 = (const float4*)src + (long)b * (L_SEQ * (DSRC / 4));
  float wt[8]; int id[8];
#pragma unroll
  for (int k = 0; k < 8; k++) {
    wt[k] = wts[(long)rowid * 8 + k];
    id[k] = idxs[(long)rowid * 8 + k];
  }
  float ax = 0, ay = 0, az = 0, aw = 0;
  float bx = 0, by = 0, bz2 = 0, bw = 0;
#pragma unroll
  for (int k = 0; k < 8; k++) {
    int r0 = id[k] + w0 - 1;
    if ((unsigned)r0 < (unsigned)L_SEQ) {
      float4 x = s4[(long)r0 * 128 + d4];
      ax += wt[k] * x.x; ay += wt[k] * x.y; az += wt[k] * x.z; aw += wt[k] * x.w;
    }
    int r1 = r0 + 1;
    if ((unsigned)r1 < (unsigned)L_SEQ) {
      float4 x = s4[(long)r1 * 128 + d4];
      bx += wt[k] * x.x; by += wt[k] * x.y; bz2 += wt[k] * x.z; bw += wt[k] * x.w;
    }
  }
  float4* o4 = (float4*)out + ((long)rowid * 4 + w0) * 128 + d4;
  o4[0] = make_float4(ax, ay, az, aw);
  o4[128] = make_float4(bx, by, bz2, bw);
}

extern "C" void kernel_launch(void* const* d_in, const int* in_sizes, int n_in,
                              void* d_out, int out_size, void* d_ws, size_t ws_size,
                              hipStream_t stream) {
  (void)in_sizes; (void)n_in; (void)out_size; (void)ws_size;
  const float* query  = (const float*)d_in[0];
  const float* key_t  = (const float*)d_in[1];
  const float* source = (const float*)d_in[2];
  const float* wq     = (const float*)d_in[3];
  const float* bq     = (const float*)d_in[4];
  const float* wk     = (const float*)d_in[5];
  const float* bk     = (const float*)d_in[6];

  char* ws = (char*)d_ws;
  // ws layout (bytes), max end 63,963,136 < proven 84,934,656:
  //   0         qs  bf16x3 planes of q (3 x 2048x1024)  12.58 MB  live: proj -> score
  //   12582912  ks  bf16x3 planes of k                  12.58 MB
  //   25165824  wts fp32 (16384x8)                      512 KB
  //   25690112  idxs i32                                512 KB
  //   26214400  xs: 6 bf16 planes (xq,xk)               25.17 MB  dead after proj
  //   51380224  wsp: 6 bf16 planes (wq,wk)              12.58 MB  dead after proj
  //   26214400  sc: per-batch scores (8x1024x1024 f32)  33.55 MB  (overlays xs/wsp)
  ushort* qs  = (ushort*)(ws);
  ushort* ksp = (ushort*)(ws + 12582912);
  float*  wts = (float*)(ws + 25165824);
  int*    idxs= (int*)(ws + 25690112);
  ushort* xs  = (ushort*)(ws + 26214400);
  ushort* wsp = (ushort*)(ws + 51380224);
  float*  sc  = (float*)(ws + 26214400);

  split_inputs_k<<<6144, 256, 0, stream>>>(query, key_t, wq, wk, xs, wsp);
  proj_gemm_k<<<dim3(8, 16, 2), 512, 0, stream>>>(xs, wsp, qs, ksp, bq, bk);
  for (int b = 0; b < 2; b++) {
    score_gemm_k<<<dim3(8, 8, 8), 512, 0, stream>>>(qs, ksp, sc, b);
    topk_softmax_k<<<2048, 256, 0, stream>>>(sc, wts + (long)b * 65536, idxs + b * 65536);
  }
  gather_out_k<<<16384, 256, 0, stream>>>(source, wts, idxs, (float*)d_out);
}